// Round 5
// baseline (548.151 us; speedup 1.0000x reference)
//
#include <hip/hip_runtime.h>

#define EPS_ALPHA 1e-5f
#define ROWS_PER_BLOCK 8

// DeepPoly ReLU6 relaxation, all six outputs per neuron.
struct Relax { float cl, cu, dl, du, bl, bu; };

__device__ __forceinline__ Relax relax6(float l, float u) {
    // guarded denominators — identical to reference so all divisions are finite
    float den_ul = (u > l)    ? (u - l)    : 1.0f;
    float den_6l = (l < 6.0f) ? (6.0f - l) : 1.0f;
    float u_safe = (u > 0.0f) ? u          : 1.0f;

    bool mA = (u > 0.0f) && (u <= 6.0f) && (l >= 0.0f);  // stable active
    bool mB = (u > 0.0f) && (u <= 6.0f) && (l < 0.0f);   // crosses 0
    bool mC = (u > 6.0f) && (l <= 0.0f);                 // crosses 0 and 6
    bool mD = (u > 6.0f) && (l > 0.0f) && (l <= 6.0f);   // crosses 6
    bool mE = (l > 6.0f);                                // saturated

    float alpha_B = (u < -l) ? EPS_ALPHA : 1.0f;
    float lam_B   = u / den_ul;
    bool  upC     = ((u - 6.0f) < (6.0f - l));
    float aU_C = upC ? (6.0f / den_6l) : EPS_ALPHA;
    float aL_C = (u < -l) ? EPS_ALPHA : (6.0f / u_safe);
    float aU_D = upC ? 1.0f : EPS_ALPHA;
    float aL_D = (6.0f - l) / den_ul;

    Relax R;
    // masks mutually exclusive; non-selected reference terms are exact 0
    R.du = mA ? 1.0f : mB ? lam_B   : mC ? aU_C : mD ? aU_D : 0.0f;
    R.dl = mA ? 1.0f : mB ? alpha_B : mC ? aL_C : mD ? aL_D : 0.0f;
    R.bu = mB ? (-lam_B * l)
         : mC ? (6.0f * (1.0f - aU_C))
         : mD ? (6.0f * (1.0f - aU_D))
         : mE ? 6.0f : 0.0f;
    R.bl = mD ? (l * (1.0f - aL_D))
         : mE ? 6.0f : 0.0f;
    R.cu = mA ? u : mB ? u
         : mC ? (6.0f + aU_C * (u - 6.0f))
         : mD ? (6.0f + aU_D * (u - 6.0f))
         : mE ? 6.0f : 0.0f;
    R.cl = mA ? l
         : mB ? (alpha_B * l)
         : mC ? (aL_C * l)
         : mD ? l
         : mE ? 6.0f : 0.0f;
    return R;
}

// One fused pass writing every logical output float exactly once.
// Matrix blocks handle ROWS_PER_BLOCK consecutive global rows (A_l rows are
// global rows [0,M), A_u rows are [M,2M)) with NO barriers: the diagonal
// element is selected branchlessly inside the streaming float4 store loop.
// The last two blocks emit the cl / cu vectors.
__global__ __launch_bounds__(256) void relu6_fused(
        const float* __restrict__ lower, const float* __restrict__ upper,
        float* __restrict__ out, int n) {
    const int tid = threadIdx.x;
    const long long M     = (long long)n + 1;
    const long long MM    = M * M;
    const long long twoM  = 2 * M;
    const long long nbMat = (twoM + ROWS_PER_BLOCK - 1) / ROWS_PER_BLOCK;
    const long long bid   = blockIdx.x;

    // ---------------- cl / cu vectors ----------------
    if (bid >= nbMat) {
        const int which = (int)(bid - nbMat);   // 0 -> cl, 1 -> cu
        float* dst = out + (long long)which * n;
        const int nv = n & ~3;
        for (int i = tid * 4; i < nv; i += 256 * 4) {
            float4 lv = *reinterpret_cast<const float4*>(lower + i);
            float4 uv = *reinterpret_cast<const float4*>(upper + i);
            Relax r0 = relax6(lv.x, uv.x), r1 = relax6(lv.y, uv.y),
                  r2 = relax6(lv.z, uv.z), r3 = relax6(lv.w, uv.w);
            float4 v;
            v.x = which ? r0.cu : r0.cl;
            v.y = which ? r1.cu : r1.cl;
            v.z = which ? r2.cu : r2.cl;
            v.w = which ? r3.cu : r3.cl;
            *reinterpret_cast<float4*>(dst + i) = v;
        }
        for (int i = nv + tid; i < n; i += 256) {
            Relax R = relax6(lower[i], upper[i]);
            dst[i] = which ? R.cu : R.cl;
        }
        return;
    }

    // ---------------- matrix rows (ROWS_PER_BLOCK per block, no barriers) ----
    const long long rowBeg = bid * ROWS_PER_BLOCK;
    const long long rowEnd = (rowBeg + ROWS_PER_BLOCK < twoM)
                           ? rowBeg + ROWS_PER_BLOCK : twoM;

    for (long long Rg = rowBeg; Rg < rowEnd; ++Rg) {
        const int       mat   = (Rg >= M) ? 1 : 0;   // 0 -> A_l, 1 -> A_u
        const long long r     = Rg - (mat ? M : 0);
        const long long start = 2LL * n + (mat ? MM : 0) + r * M;
        float* __restrict__ row = out + start;

        // 16B alignment phase differs per row (M is odd)
        const int       head      = (int)((4 - (start & 3)) & 3);
        const long long tailStart = head + ((M - head) & ~3LL);
        const long long tailLen   = M - tailStart;              // 0..3

        if (r < n) {
            // diagonal row: zeros except col r = diag value (branchless select)
            const float lr = lower[r], ur = upper[r];           // uniform
            Relax Rx = relax6(lr, ur);
            const float dval = mat ? Rx.du : Rx.dl;
            for (long long c = head + (long long)tid * 4; c < tailStart;
                 c += 256 * 4) {
                float4 v;
                v.x = (c     == r) ? dval : 0.0f;
                v.y = (c + 1 == r) ? dval : 0.0f;
                v.z = (c + 2 == r) ? dval : 0.0f;
                v.w = (c + 3 == r) ? dval : 0.0f;
                *reinterpret_cast<float4*>(row + c) = v;
            }
            if (tid < head)
                row[tid] = ((long long)tid == r) ? dval : 0.0f;
            if (tid < tailLen) {
                long long c = tailStart + tid;
                row[c] = (c == r) ? dval : 0.0f;
            }
        } else {
            // bias row (r == n): cols [0,n) = bias, col n = 1.0
            for (long long c = head + (long long)tid * 4; c < tailStart;
                 c += 256 * 4) {
                float4 v;
                #pragma unroll
                for (int j = 0; j < 4; ++j) {       // j compile-time constant
                    long long cc = c + j;
                    float val;
                    if (cc >= n) {
                        val = 1.0f;                  // cc can only be n here
                    } else {
                        Relax Rb = relax6(lower[cc], upper[cc]);
                        val = mat ? Rb.bu : Rb.bl;
                    }
                    (&v.x)[j] = val;
                }
                *reinterpret_cast<float4*>(row + c) = v;
            }
            if (tid < head) {
                long long c = tid;                   // head cols are < n
                Relax Rb = relax6(lower[c], upper[c]);
                row[c] = mat ? Rb.bu : Rb.bl;
            }
            if (tid < tailLen) {
                long long c = tailStart + tid;
                float val;
                if (c >= n) val = 1.0f;
                else { Relax Rb = relax6(lower[c], upper[c]); val = mat ? Rb.bu : Rb.bl; }
                row[c] = val;
            }
        }
    }
}

extern "C" void kernel_launch(void* const* d_in, const int* in_sizes, int n_in,
                              void* d_out, int out_size, void* d_ws, size_t ws_size,
                              hipStream_t stream) {
    const float* lower = (const float*)d_in[0];
    const float* upper = (const float*)d_in[1];
    float* out = (float*)d_out;
    int n = in_sizes[0];  // 8192

    // Single fused pass: writes every logical output float exactly once with
    // coalesced float4 streaming stores, no barriers, no separate fill pass.
    const long long M = (long long)n + 1;
    const long long twoM = 2 * M;
    const long long nbMat = (twoM + ROWS_PER_BLOCK - 1) / ROWS_PER_BLOCK;
    const long long numBlocks = nbMat + 2;   // matrix row-groups + cl + cu
    relu6_fused<<<(int)numBlocks, 256, 0, stream>>>(lower, upper, out, n);
}

// Round 6
// 515.493 us; speedup vs baseline: 1.0634x; 1.0634x over previous
//
#include <hip/hip_runtime.h>

#define EPS_ALPHA 1e-5f

// DeepPoly ReLU6 relaxation, all six outputs per neuron.
struct Relax { float cl, cu, dl, du, bl, bu; };

__device__ __forceinline__ Relax relax6(float l, float u) {
    // guarded denominators — identical to reference so all divisions are finite
    float den_ul = (u > l)    ? (u - l)    : 1.0f;
    float den_6l = (l < 6.0f) ? (6.0f - l) : 1.0f;
    float u_safe = (u > 0.0f) ? u          : 1.0f;

    bool mA = (u > 0.0f) && (u <= 6.0f) && (l >= 0.0f);  // stable active
    bool mB = (u > 0.0f) && (u <= 6.0f) && (l < 0.0f);   // crosses 0
    bool mC = (u > 6.0f) && (l <= 0.0f);                 // crosses 0 and 6
    bool mD = (u > 6.0f) && (l > 0.0f) && (l <= 6.0f);   // crosses 6
    bool mE = (l > 6.0f);                                // saturated

    float alpha_B = (u < -l) ? EPS_ALPHA : 1.0f;
    float lam_B   = u / den_ul;
    bool  upC     = ((u - 6.0f) < (6.0f - l));
    float aU_C = upC ? (6.0f / den_6l) : EPS_ALPHA;
    float aL_C = (u < -l) ? EPS_ALPHA : (6.0f / u_safe);
    float aU_D = upC ? 1.0f : EPS_ALPHA;
    float aL_D = (6.0f - l) / den_ul;

    Relax R;
    // masks mutually exclusive; non-selected reference terms are exact 0
    R.du = mA ? 1.0f : mB ? lam_B   : mC ? aU_C : mD ? aU_D : 0.0f;
    R.dl = mA ? 1.0f : mB ? alpha_B : mC ? aL_C : mD ? aL_D : 0.0f;
    R.bu = mB ? (-lam_B * l)
         : mC ? (6.0f * (1.0f - aU_C))
         : mD ? (6.0f * (1.0f - aU_D))
         : mE ? 6.0f : 0.0f;
    R.bl = mD ? (l * (1.0f - aL_D))
         : mE ? 6.0f : 0.0f;
    R.cu = mA ? u : mB ? u
         : mC ? (6.0f + aU_C * (u - 6.0f))
         : mD ? (6.0f + aU_D * (u - 6.0f))
         : mE ? 6.0f : 0.0f;
    R.cl = mA ? l
         : mB ? (alpha_B * l)
         : mC ? (aL_C * l)
         : mD ? l
         : mE ? 6.0f : 0.0f;
    return R;
}

// Sparse value scatter: one thread per neuron. The matrix zero region is
// handled by hipMemsetAsync (the rocclr blit runs at the 6.2 TB/s write
// ceiling — two fused-fill attempts, R4/R5, both measured slower).
// Launched as (n/64) blocks x 64 threads: one wave per block spread across
// 128 CUs, so the stride-32KB diagonal stores use 4x more parallel memory
// pipes than the previous 32x256 config.
__global__ __launch_bounds__(64) void relu6_scatter(
        const float* __restrict__ lower, const float* __restrict__ upper,
        float* __restrict__ out, int n) {
    int i = blockIdx.x * blockDim.x + threadIdx.x;
    if (i >= n) return;

    Relax R = relax6(lower[i], upper[i]);

    const long long M  = (long long)n + 1;   // 8193
    const long long MM = M * M;
    float* cl_p = out;
    float* cu_p = out + n;
    float* Al   = out + 2LL * n;
    float* Au   = Al + MM;

    cl_p[i] = R.cl;                           // coalesced
    cu_p[i] = R.cu;                           // coalesced
    Al[(long long)i * M + i] = R.dl;          // diagonal (stride M+1 scatter)
    Au[(long long)i * M + i] = R.du;
    Al[(long long)n * M + i] = R.bl;          // last row (coalesced)
    Au[(long long)n * M + i] = R.bu;
    if (i == 0) {
        Al[MM - 1] = 1.0f;
        Au[MM - 1] = 1.0f;
    }
}

extern "C" void kernel_launch(void* const* d_in, const int* in_sizes, int n_in,
                              void* d_out, int out_size, void* d_ws, size_t ws_size,
                              hipStream_t stream) {
    const float* lower = (const float*)d_in[0];
    const float* upper = (const float*)d_in[1];
    float* out = (float*)d_out;
    int n = in_sizes[0];  // 8192

    // Zero only the matrix region [2n, 2n + 2*M*M): the scatter kernel fully
    // writes cl/cu itself. The blit fill is the fastest known way to stream
    // zeros (6.2 TB/s measured); both single-pass fused alternatives (R4, R5)
    // measured 2.8-4.5 TB/s and regressed.
    const size_t M = (size_t)n + 1;
    hipMemsetAsync(out + 2 * (size_t)n, 0, 2 * M * M * sizeof(float), stream);

    // Sparse values: diagonals, bias rows, cl/cu, corner ones.
    relu6_scatter<<<(n + 63) / 64, 64, 0, stream>>>(lower, upper, out, n);
}